// Round 9
// baseline (166.513 us; speedup 1.0000x reference)
//
#include <hip/hip_runtime.h>

typedef unsigned short u16;
typedef unsigned int u32;
typedef __attribute__((ext_vector_type(8))) short short8;   // 8 bf16 (4 VGPRs)
typedef __attribute__((ext_vector_type(4))) float f32x4;

__device__ __forceinline__ u16 f2b(float f) {  // RNE f32 -> bf16
  union { u32 i; float f; } v; v.f = f;
  u32 i = v.i;
  return (u16)((i + 0x7FFFu + ((i >> 16) & 1u)) >> 16);
}

// Single-op packed f32x2 -> bf16x2 (RNE). lo -> low 16 bits, hi -> high.
__device__ __forceinline__ u32 cvtpk(float lo, float hi) {
  u32 r;
  asm("v_cvt_pk_bf16_f32 %0, %1, %2" : "=v"(r) : "v"(lo), "v"(hi));
  return r;
}

// Compiler-only memory barrier: pins ds_read triplets into program order
// (bounds outstanding LDS reads to 2 triplets = 24 VGPRs of buffer).
__device__ __forceinline__ void lds_compiler_fence() {
  asm volatile("" ::: "memory");
}

__device__ __forceinline__ f32x4 mfma16(short8 a, short8 b, f32x4 c) {
  return __builtin_amdgcn_mfma_f32_16x16x32_bf16(a, b, c, 0, 0, 0);
}

// R18-proven packB: relu (f32 fmax) then cvtpk.
__device__ __forceinline__ short8 packB(const f32x4& a0, const f32x4& a1) {
  union { u32 u[4]; short8 s; } fu;
  fu.u[0] = cvtpk(fmaxf(a0.x, 0.f), fmaxf(a0.y, 0.f));
  fu.u[1] = cvtpk(fmaxf(a0.z, 0.f), fmaxf(a0.w, 0.f));
  fu.u[2] = cvtpk(fmaxf(a1.x, 0.f), fmaxf(a1.y, 0.f));
  fu.u[3] = cvtpk(fmaxf(a1.z, 0.f), fmaxf(a1.w, 0.f));
  return fu.s;
}

// Issue one 3-fragment triplet of ds_read_b128s, then fence so the NEXT
// triplet's reads can't be hoisted above (keeps <=2 triplets outstanding).
#define ISS(D0, D1, D2, BASE, OFF)                                   \
  do {                                                               \
    D0 = (BASE)[(OFF)];                                              \
    D1 = (BASE)[(OFF) + 64];                                         \
    D2 = (BASE)[(OFF) + 128];                                        \
    lds_compiler_fence();                                            \
  } while (0)

// 6 MFMAs: K-accumulate 3 fragments against both tiles' activations.
#define MM3(F0, F1, F2, IA0, IA1, IA2, IB0, IB1, IB2, VA, VB)        \
  do {                                                               \
    VA = mfma16(F0, IA0, z4); VB = mfma16(F0, IB0, z4);              \
    VA = mfma16(F1, IA1, VA); VB = mfma16(F1, IB1, VB);              \
    VA = mfma16(F2, IA2, VA); VB = mfma16(F2, IB2, VB);              \
  } while (0)

#define DOT4(V, WV, ACC)                                             \
  ACC += fmaxf((V).x, 0.f) * (WV).x + fmaxf((V).y, 0.f) * (WV).y +   \
         fmaxf((V).z, 0.f) * (WV).z + fmaxf((V).w, 0.f) * (WV).w

// R23 = R18's proven main loop (44.5 us; mlp-side converged: additive-pipe
// floor LDS 45.6k + MFMA 43k + VALU 13k ~= 102k cyc vs 107k wall, and 5
// structural attempts to beat it all failed) FUSED with prep. Motivation:
// bench dur_us ~111 vs mlp 44.5 — a CONSTANT ~66 us gap (R0/R15/R16/R17/R22
// all show gap 63-67 independent of mlp time) = prep exec + extra graph node
// + prep->mlp serialization + harness memsets. Fusion removes the first
// three. Each block bakes its own tables in a prologue:
//  - W1/W2 fragment tables straight into LDS (col-fastest iteration ->
//    coalesced global reads; inverse-mapped scatter into fragment layout)
//  - w0f (per-wave o-slice) and w3v computed per-lane from W0/ac/b0/W3/b3
// Redundant across blocks but L2-hot: ~65 KB reads + ~72 f2b per thread,
// ~1-3 us of co-resident prologue. Math bit-identical to prep_kernel.
// R22 lesson pinned: VGPR must stay <=85 (6 waves/SIMD, 3 blk/CU, single
// 675-block batch); prologue temporaries die before the main loop.
__global__ __launch_bounds__(512, 2) void mlp_kernel(
    const float* __restrict__ x, const float* __restrict__ ac,
    const float* __restrict__ W0, const float* __restrict__ b0,
    const float* __restrict__ W1, const float* __restrict__ b1,
    const float* __restrict__ W2, const float* __restrict__ b2,
    const float* __restrict__ W3, const float* __restrict__ b3,
    float* __restrict__ out) {
  __shared__ short8 ldsW1[18 * 64];  // 18432 B
  __shared__ short8 ldsW2[18 * 64];  // 18432 B => 36864 B/block
  const int tid = threadIdx.x;
  const int lane = tid & 63;
  const int wv = tid >> 6;             // 0..7
  const int q = lane >> 4, n = lane & 15;

  // wave's identity: g in [0,5400) -> (o, f) bijection
  const int g = blockIdx.x * 8 + wv;
  const int o = g % 6;                 // output channel
  const int f = g / 6;                 // 0..899

  // ---- prologue A: bake W1/W2 fragment tables into LDS.
  // Iterate (which,row,col) with col fastest -> coalesced W reads; scatter
  // u16 into the fragment layout via the inverse index map (verified against
  // prep's forward map: row = 32*ki + 16*(jj>>2) + 4*qA + (jj&3),
  // col = 16*t + m, flat j2 = ((t*3+ki)<<9) | (lane<<3) | jj).
  {
    u16* lds1u = (u16*)ldsW1;
    u16* lds2u = (u16*)ldsW2;
    for (int i2 = tid; i2 < 2 * 9216; i2 += 512) {
      const int which = i2 / 9216;
      const int rc = i2 - which * 9216;
      const int row = rc / 96, col = rc - row * 96;
      const float* W = which ? W2 : W1;
      const float* bb = which ? b2 : b1;
      u16 v = 0;
      if (row < 90 && col < 90) v = f2b(W[row * 90 + col]);
      else if (row == 90) v = (col < 90) ? f2b(bb[col]) : ((col == 90) ? (u16)0x3F80 : (u16)0);
      const int t = col >> 4, m = col & 15;
      const int ki = row >> 5, r5 = row & 31;
      const int jj = ((r5 >> 4) << 2) | (r5 & 3);
      const int qA = (r5 >> 2) & 3;
      const int ln = (qA << 4) | m;
      const int j2 = (((t * 3 + ki) << 9) | (ln << 3)) | jj;
      (which ? lds2u : lds1u)[j2] = v;
    }
  }

  // ---- prologue B: per-lane w0f (this wave's o-slice, 24 VGPRs).
  // Same formulas as prep: k = q*8+jj, u = t*16+m; rowmap branchless.
  short8 w0f[6];
  {
    const int m = lane & 15;
    const int k0 = q * 8;
#pragma unroll
    for (int t = 0; t < 6; ++t) {
      const int u = t * 16 + m;
      union { u16 e[8]; short8 s; } fr;
#pragma unroll
      for (int jj = 0; jj < 8; ++jj) {
        const int k = k0 + jj;
        u16 v = 0;
        if (k < 5) {
          const int rm = (k == 0) ? 5 : (k - 1);   // rowmap {5,0,1,2,3}
          if (u < 90) v = f2b(W0[rm * 90 + u]);
        } else if (k < 10) {
          const int dd = k - 5;
          if (u < 90) {
            float c0 = ac[(o * 5 + dd) * 2 + 0], c1 = ac[(o * 5 + dd) * 2 + 1];
            v = f2b(b0[u] + c0 * W0[4 * 90 + u] + c1 * W0[6 * 90 + u]);
          } else if (u == 90) {
            v = (u16)0x3F80;  // the "1" unit
          }
        }
        fr.e[jj] = v;
      }
      w0f[t] = fr.s;
    }
  }

  // ---- prologue C: per-lane augmented W3 (24 VGPRs). w3t[i] equivalent:
  // i<90 -> W3[i], i==90 -> b3[0], else 0.
  f32x4 w3v[6];
#pragma unroll
  for (int t = 0; t < 6; ++t) {
    f32x4 wvv;
#pragma unroll
    for (int j = 0; j < 4; ++j) {
      const int u = t * 16 + q * 4 + j;
      wvv[j] = (u < 90) ? W3[u] : ((u == 90) ? b3[0] : 0.0f);
    }
    w3v[t] = wvv;
  }

  __syncthreads();  // only barrier; LDS read-only afterwards

  // wave's pair of tiles: (bb, idx) and (bb+4, idx)
  const int bb = f / 225, idx = f % 225;
  const int seg0 = bb * 6 + o;
  const int l0 = idx * 16;
  const int l = l0 + n;
  const int oh = l / 60, ow = l - oh * 60;
  const float* xrow0 = x + (bb * 4096 + oh * 64 + ow);
  const float* xrow1 = xrow0 + 4 * 4096;  // batch +4

  const short8* w1base = &ldsW1[0] + lane;  // +c*384 (+192 for hi triplet)
  const short8* w2base = &ldsW2[0] + lane;

  const f32x4 z4 = {0.f, 0.f, 0.f, 0.f};
  float outAcc0 = 0.f, outAcc1 = 0.f;

  float pa0 = xrow0[0], pa1 = xrow0[1], pa2 = xrow0[2], pa3 = xrow0[3], pa4 = xrow0[4];
  float pb0 = xrow1[0], pb1 = xrow1[1], pb2 = xrow1[2], pb3 = xrow1[3], pb4 = xrow1[4];

#pragma unroll 1
  for (int d = 0; d < 5; ++d) {
    float a0 = pa0, a1 = pa1, a2 = pa2, a3 = pa3, a4 = pa4;
    float b0v = pb0, b1v = pb1, b2v = pb2, b3v = pb3, b4v = pb4;
    if (d < 4) {
      const float* xp0 = xrow0 + (d + 1) * 64;
      const float* xp1 = xrow1 + (d + 1) * 64;
      pa0 = xp0[0]; pa1 = xp0[1]; pa2 = xp0[2]; pa3 = xp0[3]; pa4 = xp0[4];
      pb0 = xp1[0]; pb1 = xp1[1]; pb2 = xp1[2]; pb3 = xp1[3]; pb4 = xp1[4];
    }

    // one-hot(d) bias-selector slots k=5..9 (wave-uniform -> SALU)
    const u32 u3c = (d == 1) ? 0x00003F80u : ((d == 2) ? 0x3F800000u : 0u);  // k6,k7
    const u32 q1c = (d == 3) ? 0x00003F80u : ((d == 4) ? 0x3F800000u : 0u);  // k8,k9
    const float k5f = (d == 0) ? 1.0f : 0.0f;                                // k5

    union { u32 u[4]; short8 s; } bu0, bu1;
    u32 ta = cvtpk(a0, a1), tb = cvtpk(b0v, b1v);
    bu0.u[0] = (q == 1) ? q1c : ta;
    bu1.u[0] = (q == 1) ? q1c : tb;
    bu0.u[1] = cvtpk(a2, a3);   bu1.u[1] = cvtpk(b2v, b3v);
    bu0.u[2] = cvtpk(a4, k5f);  bu1.u[2] = cvtpk(b4v, k5f);
    bu0.u[3] = u3c;             bu1.u[3] = u3c;
    short8 bx0 = bu0.s, bx1 = bu1.s;

    short8 A0, A1, A2, B0, B1, B2;
    ISS(A0, A1, A2, w1base, 0);  // warm-up: L2 c0 lo, latency hidden under L1

    // ---- L1: both tiles, pack immediately (12 MFMA cover the warm-up read)
    short8 h00, h01, h02, h10, h11, h12;
    {
      f32x4 t0 = mfma16(w0f[0], bx0, z4);
      f32x4 t1 = mfma16(w0f[1], bx0, z4);
      f32x4 t2 = mfma16(w0f[0], bx1, z4);
      f32x4 t3 = mfma16(w0f[1], bx1, z4);
      h00 = packB(t0, t1); h10 = packB(t2, t3);
      t0 = mfma16(w0f[2], bx0, z4); t1 = mfma16(w0f[3], bx0, z4);
      t2 = mfma16(w0f[2], bx1, z4); t3 = mfma16(w0f[3], bx1, z4);
      h01 = packB(t0, t1); h11 = packB(t2, t3);
      t0 = mfma16(w0f[4], bx0, z4); t1 = mfma16(w0f[5], bx0, z4);
      t2 = mfma16(w0f[4], bx1, z4); t3 = mfma16(w0f[5], bx1, z4);
      h02 = packB(t0, t1); h12 = packB(t2, t3);
    }

    short8 g00, g01, g02, g10, g11, g12;
    f32x4 vX0, vX1, vY0, vY1;

    // ---- L2: 6 pipelined stages (issue next triplet, compute current)
    ISS(B0, B1, B2, w1base, 192);                               // c0 hi
    MM3(A0, A1, A2, h00, h01, h02, h10, h11, h12, vX0, vX1);    // c0 lo
    ISS(A0, A1, A2, w1base, 384);                               // c1 lo
    MM3(B0, B1, B2, h00, h01, h02, h10, h11, h12, vY0, vY1);    // c0 hi
    g00 = packB(vX0, vY0); g10 = packB(vX1, vY1);
    ISS(B0, B1, B2, w1base, 384 + 192);                         // c1 hi
    MM3(A0, A1, A2, h00, h01, h02, h10, h11, h12, vX0, vX1);    // c1 lo
    ISS(A0, A1, A2, w1base, 768);                               // c2 lo
    MM3(B0, B1, B2, h00, h01, h02, h10, h11, h12, vY0, vY1);    // c1 hi
    g01 = packB(vX0, vY0); g11 = packB(vX1, vY1);
    ISS(B0, B1, B2, w1base, 768 + 192);                         // c2 hi
    MM3(A0, A1, A2, h00, h01, h02, h10, h11, h12, vX0, vX1);    // c2 lo
    ISS(A0, A1, A2, w2base, 0);                                 // L3 c0 lo
    MM3(B0, B1, B2, h00, h01, h02, h10, h11, h12, vY0, vY1);    // c2 hi
    g02 = packB(vX0, vY0); g12 = packB(vX1, vY1);

    // ---- L3: same pipeline, dot with resident w3v instead of pack
    ISS(B0, B1, B2, w2base, 192);                               // c0 hi
    MM3(A0, A1, A2, g00, g01, g02, g10, g11, g12, vX0, vX1);    // c0 lo
    ISS(A0, A1, A2, w2base, 384);                               // c1 lo
    MM3(B0, B1, B2, g00, g01, g02, g10, g11, g12, vY0, vY1);    // c0 hi
    DOT4(vX0, w3v[0], outAcc0); DOT4(vY0, w3v[1], outAcc0);
    DOT4(vX1, w3v[0], outAcc1); DOT4(vY1, w3v[1], outAcc1);
    ISS(B0, B1, B2, w2base, 384 + 192);                         // c1 hi
    MM3(A0, A1, A2, g00, g01, g02, g10, g11, g12, vX0, vX1);    // c1 lo
    ISS(A0, A1, A2, w2base, 768);                               // c2 lo
    MM3(B0, B1, B2, g00, g01, g02, g10, g11, g12, vY0, vY1);    // c1 hi
    DOT4(vX0, w3v[2], outAcc0); DOT4(vY0, w3v[3], outAcc0);
    DOT4(vX1, w3v[2], outAcc1); DOT4(vY1, w3v[3], outAcc1);
    ISS(B0, B1, B2, w2base, 768 + 192);                         // c2 hi
    MM3(A0, A1, A2, g00, g01, g02, g10, g11, g12, vX0, vX1);    // c2 lo
    MM3(B0, B1, B2, g00, g01, g02, g10, g11, g12, vY0, vY1);    // c2 hi
    DOT4(vX0, w3v[4], outAcc0); DOT4(vY0, w3v[5], outAcc0);
    DOT4(vX1, w3v[4], outAcc1); DOT4(vY1, w3v[5], outAcc1);
  }  // d

  // reduce quad-partials and store both tiles
  outAcc0 += __shfl_xor(outAcc0, 16, 64);
  outAcc0 += __shfl_xor(outAcc0, 32, 64);
  outAcc1 += __shfl_xor(outAcc1, 16, 64);
  outAcc1 += __shfl_xor(outAcc1, 32, 64);
  if (lane < 16) {
    out[seg0 * 3600 + l0 + lane] = outAcc0;
    out[(seg0 + 24) * 3600 + l0 + lane] = outAcc1;
  }
}

extern "C" void kernel_launch(void* const* d_in, const int* in_sizes, int n_in,
                              void* d_out, int out_size, void* d_ws, size_t ws_size,
                              hipStream_t stream) {
  const float* x  = (const float*)d_in[0];
  const float* ac = (const float*)d_in[1];
  const float* W0 = (const float*)d_in[2];
  const float* b0 = (const float*)d_in[3];
  const float* W1 = (const float*)d_in[4];
  const float* b1 = (const float*)d_in[5];
  const float* W2 = (const float*)d_in[6];
  const float* b2 = (const float*)d_in[7];
  const float* W3 = (const float*)d_in[8];
  const float* b3 = (const float*)d_in[9];
  float* out = (float*)d_out;
  (void)d_ws; (void)ws_size;  // fused kernel: no workspace, single launch
  mlp_kernel<<<675, 512, 0, stream>>>(x, ac, W0, b0, W1, b1, W2, b2, W3, b3, out);
}

// Round 10
// 110.548 us; speedup vs baseline: 1.5062x; 1.5062x over previous
//
#include <hip/hip_runtime.h>

typedef unsigned short u16;
typedef unsigned int u32;
typedef __attribute__((ext_vector_type(8))) short short8;   // 8 bf16 (4 VGPRs)
typedef __attribute__((ext_vector_type(4))) float f32x4;

// ws layout (bytes), all 16B-aligned
#define WS_W3T  0        // float[96]  (W3 augmented: [90]=b3, [91..95]=0)
#define WS_W0F  384      // u16[6][6*64*8]  per-o L1 fragments w/ bias rows k=5..9
#define WS_W1F  37248    // u16[18*64*8]
#define WS_W2F  55680    // u16[18*64*8]   (ends 74112)

__device__ __forceinline__ u16 f2b(float f) {  // RNE f32 -> bf16 (prep only)
  union { u32 i; float f; } v; v.f = f;
  u32 i = v.i;
  return (u16)((i + 0x7FFFu + ((i >> 16) & 1u)) >> 16);
}

// Single-op packed f32x2 -> bf16x2 (RNE). lo -> low 16 bits, hi -> high.
__device__ __forceinline__ u32 cvtpk(float lo, float hi) {
  u32 r;
  asm("v_cvt_pk_bf16_f32 %0, %1, %2" : "=v"(r) : "v"(lo), "v"(hi));
  return r;
}

// Compiler-only memory barrier: pins ds_read triplets into program order
// (bounds outstanding LDS reads to 2 triplets = 24 VGPRs of buffer).
__device__ __forceinline__ void lds_compiler_fence() {
  asm volatile("" ::: "memory");
}

// prep: identical math to R8-R13 (verified absmax 7.8e-3). Two-kernel split
// is the PROVEN design: R23's fusion (per-block table baking) cost +75 us of
// redundant prologue (x675 blocks) against only ~20 us of node savings.
__global__ void prep_kernel(const float* __restrict__ ac, const float* __restrict__ W0,
                            const float* __restrict__ b0, const float* __restrict__ W1,
                            const float* __restrict__ b1, const float* __restrict__ W2,
                            const float* __restrict__ b2, const float* __restrict__ W3,
                            const float* __restrict__ b3,
                            float* __restrict__ w3t, u16* __restrict__ W0f,
                            u16* __restrict__ W1f, u16* __restrict__ W2f) {
  int tid = blockIdx.x * blockDim.x + threadIdx.x;
  int nth = gridDim.x * blockDim.x;
  for (int i = tid; i < 96; i += nth)
    w3t[i] = (i < 90) ? W3[i] : ((i == 90) ? b3[0] : 0.0f);
  for (int i = tid; i < 6 * 6 * 64 * 8; i += nth) {
    int o = i / 3072, rem = i % 3072;
    int t = rem >> 9, lane = (rem >> 3) & 63, jj = rem & 7;
    int q = lane >> 4, m = lane & 15;
    int k = q * 8 + jj;
    int u = t * 16 + m;
    u16 v = 0;
    if (k < 5) {
      const int rowmap[5] = {5, 0, 1, 2, 3};
      if (u < 90) v = f2b(W0[rowmap[k] * 90 + u]);
    } else if (k < 10) {
      int dd = k - 5;
      if (u < 90) {
        float c0 = ac[(o * 5 + dd) * 2 + 0], c1 = ac[(o * 5 + dd) * 2 + 1];
        v = f2b(b0[u] + c0 * W0[4 * 90 + u] + c1 * W0[6 * 90 + u]);
      } else if (u == 90) {
        v = (u16)0x3F80;  // the "1" unit
      }
    }
    W0f[i] = v;
  }
  for (int i = tid; i < 2 * 18 * 64 * 8; i += nth) {
    int which = i / (18 * 64 * 8);
    int j2 = i % (18 * 64 * 8);
    int jj = j2 & 7, lane = (j2 >> 3) & 63, f = j2 >> 9;
    int t = f / 3, ki = f % 3;
    int qA = lane >> 4, m = lane & 15;
    int row = 32 * ki + 16 * (jj >> 2) + 4 * qA + (jj & 3);
    int col = 16 * t + m;
    const float* W = which ? W2 : W1;
    const float* bb = which ? b2 : b1;
    u16 v = 0;
    if (row < 90 && col < 90) v = f2b(W[row * 90 + col]);
    else if (row == 90) v = (col < 90) ? f2b(bb[col]) : ((col == 90) ? (u16)0x3F80 : (u16)0);
    (which ? W2f : W1f)[j2] = v;
  }
}

__device__ __forceinline__ f32x4 mfma16(short8 a, short8 b, f32x4 c) {
  return __builtin_amdgcn_mfma_f32_16x16x32_bf16(a, b, c, 0, 0, 0);
}

// R18-proven packB: relu (f32 fmax) then cvtpk.
__device__ __forceinline__ short8 packB(const f32x4& a0, const f32x4& a1) {
  union { u32 u[4]; short8 s; } fu;
  fu.u[0] = cvtpk(fmaxf(a0.x, 0.f), fmaxf(a0.y, 0.f));
  fu.u[1] = cvtpk(fmaxf(a0.z, 0.f), fmaxf(a0.w, 0.f));
  fu.u[2] = cvtpk(fmaxf(a1.x, 0.f), fmaxf(a1.y, 0.f));
  fu.u[3] = cvtpk(fmaxf(a1.z, 0.f), fmaxf(a1.w, 0.f));
  return fu.s;
}

// Issue one 3-fragment triplet of ds_read_b128s, then fence so the NEXT
// triplet's reads can't be hoisted above (keeps <=2 triplets outstanding).
#define ISS(D0, D1, D2, BASE, OFF)                                   \
  do {                                                               \
    D0 = (BASE)[(OFF)];                                              \
    D1 = (BASE)[(OFF) + 64];                                         \
    D2 = (BASE)[(OFF) + 128];                                        \
    lds_compiler_fence();                                            \
  } while (0)

// 6 MFMAs: K-accumulate 3 fragments against both tiles' activations.
#define MM3(F0, F1, F2, IA0, IA1, IA2, IB0, IB1, IB2, VA, VB)        \
  do {                                                               \
    VA = mfma16(F0, IA0, z4); VB = mfma16(F0, IB0, z4);              \
    VA = mfma16(F1, IA1, VA); VB = mfma16(F1, IB1, VB);              \
    VA = mfma16(F2, IA2, VA); VB = mfma16(F2, IB2, VB);              \
  } while (0)

#define DOT4(V, WV, ACC)                                             \
  ACC += fmaxf((V).x, 0.f) * (WV).x + fmaxf((V).y, 0.f) * (WV).y +   \
         fmaxf((V).z, 0.f) * (WV).z + fmaxf((V).w, 0.f) * (WV).w

// R24 = R18 revert (best verified: mlp 44.5 us, bench 110.8 us). Session
// ledger: mlp is converged — additive-pipe floor (LDS 45.6k + MFMA 43k +
// VALU 13k ~= 102k cyc vs 107k wall) and SIX structural attempts all failed:
// 2-stage pipeline (+19%), setprio (+19%), stagger (+8%), reg-resident W1
// (+17%, VGPR>85 breaks single-batch residency), 8-wave repack (0%), prep
// fusion (-55 us net: x675 redundant per-block baking swamps ~20 us node
// saving). Hard constraints pinned: VGPR <= 85 (6 waves/SIMD, 3 blk/CU,
// single 675-block batch); launch_bounds 2nd arg = min BLOCKS/CU on hipcc.
// Only tweak vs R18: prep grid 128 -> 288 blocks (grid-stride safe; <=1
// item/thread on all prep loops).
__global__ __launch_bounds__(512, 2) void mlp_kernel(
    const float* __restrict__ x, const float* __restrict__ w3t,
    const u16* __restrict__ W0f, const u16* __restrict__ W1f,
    const u16* __restrict__ W2f, float* __restrict__ out) {
  __shared__ short8 ldsW1[18 * 64];  // 18432 B
  __shared__ short8 ldsW2[18 * 64];  // 18432 B => 36864 B/block
  const int tid = threadIdx.x;
  {  // cooperative one-time fill (512 threads, 1152 uint4 per array)
    const uint4* s1 = (const uint4*)W1f;
    const uint4* s2 = (const uint4*)W2f;
    uint4* d1 = (uint4*)ldsW1;
    uint4* d2 = (uint4*)ldsW2;
#pragma unroll
    for (int i = 0; i < 3; ++i) {
      int j = tid + i * 512;
      if (j < 1152) { d1[j] = s1[j]; d2[j] = s2[j]; }
    }
  }
  __syncthreads();  // only barrier; LDS read-only afterwards

  const int lane = tid & 63;
  const int wv = tid >> 6;             // 0..7
  const int q = lane >> 4, n = lane & 15;

  // wave's identity: g in [0,5400) -> (o, f) bijection
  const int g = blockIdx.x * 8 + wv;
  const int o = g % 6;                 // output channel
  const int f = g / 6;                 // 0..899

  // resident o-specific L1 fragments (24 VGPRs) + augmented W3 (24 VGPRs)
  short8 w0f[6];
  const short8* p0 = (const short8*)W0f + o * 384;
#pragma unroll
  for (int t = 0; t < 6; ++t) w0f[t] = p0[t * 64 + lane];
  f32x4 w3v[6];
#pragma unroll
  for (int t = 0; t < 6; ++t) w3v[t] = *(const f32x4*)(w3t + t * 16 + q * 4);

  // wave's pair of tiles: (bb, idx) and (bb+4, idx)
  const int bb = f / 225, idx = f % 225;
  const int seg0 = bb * 6 + o;
  const int l0 = idx * 16;
  const int l = l0 + n;
  const int oh = l / 60, ow = l - oh * 60;
  const float* xrow0 = x + (bb * 4096 + oh * 64 + ow);
  const float* xrow1 = xrow0 + 4 * 4096;  // batch +4

  const short8* w1base = &ldsW1[0] + lane;  // +c*384 (+192 for hi triplet)
  const short8* w2base = &ldsW2[0] + lane;

  const f32x4 z4 = {0.f, 0.f, 0.f, 0.f};
  float outAcc0 = 0.f, outAcc1 = 0.f;

  float pa0 = xrow0[0], pa1 = xrow0[1], pa2 = xrow0[2], pa3 = xrow0[3], pa4 = xrow0[4];
  float pb0 = xrow1[0], pb1 = xrow1[1], pb2 = xrow1[2], pb3 = xrow1[3], pb4 = xrow1[4];

#pragma unroll 1
  for (int d = 0; d < 5; ++d) {
    float a0 = pa0, a1 = pa1, a2 = pa2, a3 = pa3, a4 = pa4;
    float b0 = pb0, b1 = pb1, b2 = pb2, b3 = pb3, b4 = pb4;
    if (d < 4) {
      const float* xp0 = xrow0 + (d + 1) * 64;
      const float* xp1 = xrow1 + (d + 1) * 64;
      pa0 = xp0[0]; pa1 = xp0[1]; pa2 = xp0[2]; pa3 = xp0[3]; pa4 = xp0[4];
      pb0 = xp1[0]; pb1 = xp1[1]; pb2 = xp1[2]; pb3 = xp1[3]; pb4 = xp1[4];
    }

    // one-hot(d) bias-selector slots k=5..9 (wave-uniform -> SALU)
    const u32 u3c = (d == 1) ? 0x00003F80u : ((d == 2) ? 0x3F800000u : 0u);  // k6,k7
    const u32 q1c = (d == 3) ? 0x00003F80u : ((d == 4) ? 0x3F800000u : 0u);  // k8,k9
    const float k5f = (d == 0) ? 1.0f : 0.0f;                                // k5

    union { u32 u[4]; short8 s; } bu0, bu1;
    u32 ta = cvtpk(a0, a1), tb = cvtpk(b0, b1);
    bu0.u[0] = (q == 1) ? q1c : ta;
    bu1.u[0] = (q == 1) ? q1c : tb;
    bu0.u[1] = cvtpk(a2, a3);  bu1.u[1] = cvtpk(b2, b3);
    bu0.u[2] = cvtpk(a4, k5f); bu1.u[2] = cvtpk(b4, k5f);
    bu0.u[3] = u3c;            bu1.u[3] = u3c;
    short8 bx0 = bu0.s, bx1 = bu1.s;

    short8 A0, A1, A2, B0, B1, B2;
    ISS(A0, A1, A2, w1base, 0);  // warm-up: L2 c0 lo, latency hidden under L1

    // ---- L1: both tiles, pack immediately (12 MFMA cover the warm-up read)
    short8 h00, h01, h02, h10, h11, h12;
    {
      f32x4 t0 = mfma16(w0f[0], bx0, z4);
      f32x4 t1 = mfma16(w0f[1], bx0, z4);
      f32x4 t2 = mfma16(w0f[0], bx1, z4);
      f32x4 t3 = mfma16(w0f[1], bx1, z4);
      h00 = packB(t0, t1); h10 = packB(t2, t3);
      t0 = mfma16(w0f[2], bx0, z4); t1 = mfma16(w0f[3], bx0, z4);
      t2 = mfma16(w0f[2], bx1, z4); t3 = mfma16(w0f[3], bx1, z4);
      h01 = packB(t0, t1); h11 = packB(t2, t3);
      t0 = mfma16(w0f[4], bx0, z4); t1 = mfma16(w0f[5], bx0, z4);
      t2 = mfma16(w0f[4], bx1, z4); t3 = mfma16(w0f[5], bx1, z4);
      h02 = packB(t0, t1); h12 = packB(t2, t3);
    }

    short8 g00, g01, g02, g10, g11, g12;
    f32x4 vX0, vX1, vY0, vY1;

    // ---- L2: 6 pipelined stages (issue next triplet, compute current)
    ISS(B0, B1, B2, w1base, 192);                               // c0 hi
    MM3(A0, A1, A2, h00, h01, h02, h10, h11, h12, vX0, vX1);    // c0 lo
    ISS(A0, A1, A2, w1base, 384);                               // c1 lo
    MM3(B0, B1, B2, h00, h01, h02, h10, h11, h12, vY0, vY1);    // c0 hi
    g00 = packB(vX0, vY0); g10 = packB(vX1, vY1);
    ISS(B0, B1, B2, w1base, 384 + 192);                         // c1 hi
    MM3(A0, A1, A2, h00, h01, h02, h10, h11, h12, vX0, vX1);    // c1 lo
    ISS(A0, A1, A2, w1base, 768);                               // c2 lo
    MM3(B0, B1, B2, h00, h01, h02, h10, h11, h12, vY0, vY1);    // c1 hi
    g01 = packB(vX0, vY0); g11 = packB(vX1, vY1);
    ISS(B0, B1, B2, w1base, 768 + 192);                         // c2 hi
    MM3(A0, A1, A2, h00, h01, h02, h10, h11, h12, vX0, vX1);    // c2 lo
    ISS(A0, A1, A2, w2base, 0);                                 // L3 c0 lo
    MM3(B0, B1, B2, h00, h01, h02, h10, h11, h12, vY0, vY1);    // c2 hi
    g02 = packB(vX0, vY0); g12 = packB(vX1, vY1);

    // ---- L3: same pipeline, dot with resident w3v instead of pack
    ISS(B0, B1, B2, w2base, 192);                               // c0 hi
    MM3(A0, A1, A2, g00, g01, g02, g10, g11, g12, vX0, vX1);    // c0 lo
    ISS(A0, A1, A2, w2base, 384);                               // c1 lo
    MM3(B0, B1, B2, g00, g01, g02, g10, g11, g12, vY0, vY1);    // c0 hi
    DOT4(vX0, w3v[0], outAcc0); DOT4(vY0, w3v[1], outAcc0);
    DOT4(vX1, w3v[0], outAcc1); DOT4(vY1, w3v[1], outAcc1);
    ISS(B0, B1, B2, w2base, 384 + 192);                         // c1 hi
    MM3(A0, A1, A2, g00, g01, g02, g10, g11, g12, vX0, vX1);    // c1 lo
    ISS(A0, A1, A2, w2base, 768);                               // c2 lo
    MM3(B0, B1, B2, g00, g01, g02, g10, g11, g12, vY0, vY1);    // c1 hi
    DOT4(vX0, w3v[2], outAcc0); DOT4(vY0, w3v[3], outAcc0);
    DOT4(vX1, w3v[2], outAcc1); DOT4(vY1, w3v[3], outAcc1);
    ISS(B0, B1, B2, w2base, 768 + 192);                         // c2 hi
    MM3(A0, A1, A2, g00, g01, g02, g10, g11, g12, vX0, vX1);    // c2 lo
    MM3(B0, B1, B2, g00, g01, g02, g10, g11, g12, vY0, vY1);    // c2 hi
    DOT4(vX0, w3v[4], outAcc0); DOT4(vY0, w3v[5], outAcc0);
    DOT4(vX1, w3v[4], outAcc1); DOT4(vY1, w3v[5], outAcc1);
  }  // d

  // reduce quad-partials and store both tiles
  outAcc0 += __shfl_xor(outAcc0, 16, 64);
  outAcc0 += __shfl_xor(outAcc0, 32, 64);
  outAcc1 += __shfl_xor(outAcc1, 16, 64);
  outAcc1 += __shfl_xor(outAcc1, 32, 64);
  if (lane < 16) {
    out[seg0 * 3600 + l0 + lane] = outAcc0;
    out[(seg0 + 24) * 3600 + l0 + lane] = outAcc1;
  }
}

extern "C" void kernel_launch(void* const* d_in, const int* in_sizes, int n_in,
                              void* d_out, int out_size, void* d_ws, size_t ws_size,
                              hipStream_t stream) {
  const float* x  = (const float*)d_in[0];
  const float* ac = (const float*)d_in[1];
  const float* W0 = (const float*)d_in[2];
  const float* b0 = (const float*)d_in[3];
  const float* W1 = (const float*)d_in[4];
  const float* b1 = (const float*)d_in[5];
  const float* W2 = (const float*)d_in[6];
  const float* b2 = (const float*)d_in[7];
  const float* W3 = (const float*)d_in[8];
  const float* b3 = (const float*)d_in[9];
  float* out = (float*)d_out;
  char* ws = (char*)d_ws;
  float* w3t = (float*)(ws + WS_W3T);
  u16* W0f = (u16*)(ws + WS_W0F);
  u16* W1f = (u16*)(ws + WS_W1F);
  u16* W2f = (u16*)(ws + WS_W2F);
  prep_kernel<<<288, 256, 0, stream>>>(ac, W0, b0, W1, b1, W2, b2, W3, b3,
                                       w3t, W0f, W1f, W2f);
  mlp_kernel<<<675, 512, 0, stream>>>(x, w3t, W0f, W1f, W2f, out);
}